// Round 7
// baseline (505.566 us; speedup 1.0000x reference)
//
#include <hip/hip_runtime.h>
#include <hip/hip_cooperative_groups.h>

namespace cg = cooperative_groups;

// x: [B=64, C=2048, J=8] fp32 ; W: [K=32, C=2048, I=16, J=8] fp32
// out v: [B=64, K=32, I=16] fp32
#define Cn 2048
#define EPSf 1e-7f

#define NOUT 32768            // B*K*I
#define KJ   16384            // (c,j) contraction length
#define KS1  64               // P1 k-splits (8 ksteps of 32 each)
#define KS2  16               // P5 k-splits (32 ksteps of 32 each)

typedef short bf8v __attribute__((ext_vector_type(8)));   // 8 bf16 in 4 VGPRs
typedef float f4v  __attribute__((ext_vector_type(4)));

union U16B { uint4 u; bf8v v; unsigned short h[8]; };

__device__ __forceinline__ unsigned short f2bf(float f) {
    unsigned u = __float_as_uint(f);
    u += 0x7FFF + ((u >> 16) & 1);          // round-to-nearest-even
    return (unsigned short)(u >> 16);
}
// 2 f32 -> packed bf16x2 (RNE). No builtin on gfx950; single VOP3 instr.
__device__ __forceinline__ unsigned cvtpk(float lo, float hi) {
    unsigned r;
    asm("v_cvt_pk_bf16_f32 %0, %1, %2" : "=v"(r) : "v"(lo), "v"(hi));
    return r;
}
__device__ __forceinline__ float bflo(unsigned u) { return __uint_as_float(u << 16); }
__device__ __forceinline__ float bfhi(unsigned u) { return __uint_as_float(u & 0xffff0000u); }

// ---------------------------------------------------------------------------
// kFused: 7 phases, 512 blocks x 256 threads.  phase==-1: cooperative, all
// phases separated by grid.sync() (2x co-residency margin at 4 blocks/CU).
// phase==p: regular launch running only phase p (fallback = 7 launches,
// byte-identical math to the proven round-5 pipeline).
// ws layout (float offsets), total 21.04 MB:
//   [0 .. 4194304)        agr/cc [k][c][b] fp32 (16 MiB); part1 (KS1*NOUT =
//                         2M floats) aliases agr[0:2M] (dead before P3).
//   [4194304 .. +524288)  xb bf16 [b][cj]
//   [4718592 .. +524288)  xT2 bf16 [cj/4][b][4]; part2 (KS2*NOUT = 512K
//                         floats) aliases xT2 exactly (xT2 dead after P3).
//   [5242880 .. +16384)   v1f bf16 B-frags (64 KiB)
// ---------------------------------------------------------------------------
__global__ __launch_bounds__(256, 4) void kFused(const float* __restrict__ x,
                                                 const float* __restrict__ W,
                                                 float* __restrict__ out,
                                                 float* __restrict__ wsf,
                                                 int phase)
{
    float*          agr   = wsf;
    float*          part1 = wsf;
    unsigned short* xb    = (unsigned short*)(wsf + 4194304);
    unsigned short* xT2   = (unsigned short*)(wsf + 4718592);
    float*          part2 = wsf + 4718592;
    unsigned short* v1f   = (unsigned short*)(wsf + 5242880);

    cg::grid_group grid = cg::this_grid();
    const int  bid  = blockIdx.x;      // 0..511
    const int  tid  = threadIdx.x;     // 0..255
    const int  lane = tid & 63;
    const bool all  = (phase < 0);

    __shared__ float  shA[4][65];      // P2 sub-reduction
    __shared__ float4 shB[256];        // P6 split-reduction

    // ---- P0: prepX — x fp32 -> xb bf16 [b][cj] + xT2 bf16 [cj/4][b][4].
    if (all || phase == 0) {
        const int g = bid * 256 + tid;           // 0..131071 = b*2048+c
        const float4* s = (const float4*)(x + (size_t)g * 8);
        float4 a = s[0], b4 = s[1];
        U16B o;
        o.h[0] = f2bf(a.x);  o.h[1] = f2bf(a.y);  o.h[2] = f2bf(a.z);  o.h[3] = f2bf(a.w);
        o.h[4] = f2bf(b4.x); o.h[5] = f2bf(b4.y); o.h[6] = f2bf(b4.z); o.h[7] = f2bf(b4.w);
        ((uint4*)xb)[g] = o.u;
        const int b = g >> 11, c = g & 2047;
        *(uint2*)(xT2 + ((size_t)(c * 2 + 0) * 64 + b) * 4) = make_uint2(o.u.x, o.u.y);
        *(uint2*)(xT2 + ((size_t)(c * 2 + 1) * 64 + b) * 4) = make_uint2(o.u.z, o.u.w);
    }
    if (all) grid.sync();

    // ---- P1: gemm1 — D[b, n=(k,i)] = sum_cj x[b,cj]*W[cj,n] partials.
    // 512 blocks = 8 nstrips x 64 ksplits (8 ksteps each); W bf16-ized on
    // the fly via v_cvt_pk_bf16_f32 (proven round-5 shape).
    if (all || phase == 1) {
        const int nstrip = bid & 7;
        const int ksplit = bid >> 3;             // 0..63
        const int ks0    = ksplit * 8;
        const int m0     = (tid >> 6) * 16;
        const int i      = lane & 15;
        const int cq     = lane >> 4;

        f4v acc[4] = {};
        const unsigned short* arow = xb + (size_t)(m0 + i) * KJ + cq * 8;

        for (int s = 0; s < 8; ++s) {
            const int ks = ks0 + s;
            U16B af;
            af.u = *(const uint4*)(arow + (size_t)ks * 32);
            const int c = ks * 4 + cq;
            #pragma unroll
            for (int t = 0; t < 4; ++t) {
                const int ko = nstrip * 4 + t;
                const float* wp = W + (((size_t)ko * Cn + c) * 16 + i) * 8;
                const float4 w0 = *(const float4*)wp;
                const float4 w1 = *(const float4*)(wp + 4);
                U16B bf;
                bf.u.x = cvtpk(w0.x, w0.y); bf.u.y = cvtpk(w0.z, w0.w);
                bf.u.z = cvtpk(w1.x, w1.y); bf.u.w = cvtpk(w1.z, w1.w);
                acc[t] = __builtin_amdgcn_mfma_f32_16x16x32_bf16(af.v, bf.v, acc[t], 0, 0, 0);
            }
        }
        // C/D layout: col = lane&15, row = (lane>>4)*4 + reg (verified m89/m91)
        float* pb = part1 + (size_t)ksplit * NOUT;
        const int col = lane & 15, rbase = (lane >> 4) * 4;
        #pragma unroll
        for (int t = 0; t < 4; ++t) {
            const int n = (nstrip * 4 + t) * 16 + col;
            #pragma unroll
            for (int r = 0; r < 4; ++r)
                pb[(size_t)(m0 + rbase + r) * 512 + n] = acc[t][r];
        }
    }
    if (all) grid.sync();

    // ---- P2: sq1 — v1 = squash((1/32)*sum_splits part1) -> bf16 B-frags.
    // Block bid owns items bid*64..+63; 4 subs x 16 splits each, LDS tree.
    if (all || phase == 2) {
        const int itemL = tid & 63, sub = tid >> 6;   // sub 0..3
        const int item  = bid * 64 + itemL;           // 0..32767 = ((b*32)+k)*16+i
        float s = 0.f;
        #pragma unroll 4
        for (int g = 0; g < 16; ++g)
            s += part1[(size_t)(sub * 16 + g) * NOUT + item];
        shA[sub][itemL] = s;
        __syncthreads();
        if (tid < 64) {
            float s2 = (shA[0][tid] + shA[1][tid]) + (shA[2][tid] + shA[3][tid]);
            s2 *= (1.0f / 32.0f);                     // softmax(0) over k = 1/32
            float sq = s2 * s2;                       // reduce over the 16 i's
            sq += __shfl_xor(sq, 1);
            sq += __shfl_xor(sq, 2);
            sq += __shfl_xor(sq, 4);
            sq += __shfl_xor(sq, 8);
            const float f = (sq / (1.0f + sq)) * rsqrtf(sq + EPSf);
            const float v = s2 * f;
            const int it = bid * 64 + tid;
            const int b = it >> 9, k = (it >> 4) & 31, ii = it & 15;
            // B-frag slot: lane = (i>>3)*16 + (b&15)
            const int pos = ((k * 4 + (b >> 4)) * 32 + (ii >> 3) * 16 + (b & 15)) * 8 + (ii & 7);
            v1f[pos] = f2bf(v);
        }
    }
    if (all) grid.sync();

    // ---- P3: agr — agreement via MFMA, u never materialized.
    // Per k: D[m=(c,j), n=b] = sum_i W[k,c,i,j]*v1[b,k,i] (i padded to 32),
    // epilogue A[b,k,c] = sum_j x[b,c,j]*D via 4 FMA + shfl_xor(16).
    // 512 blocks = 32 k x 16 c-groups (128 c each).
    if (all || phase == 3) {
        const int ko  = bid & 31;
        const int cgi = bid >> 5;                 // 0..15
        const int w   = tid >> 6;

        U16B bfr[4];
        #pragma unroll
        for (int nt = 0; nt < 4; ++nt) {
            if (lane < 32)
                bfr[nt].u = *(const uint4*)(v1f + ((size_t)(ko * 4 + nt) * 32 + lane) * 8);
            else
                bfr[nt].u = make_uint4(0, 0, 0, 0);
        }

        for (int mt = w; mt < 64; mt += 4) {      // 16 m-tiles per wave
            const int cjb = cgi * 1024 + mt * 16;
            U16B afr;                             // A-frag: m=cj, kdim=i
            if (lane < 32) {
                const int cj = cjb + (lane & 15);
                const int c = cj >> 3, j = cj & 7;
                const int ib = (lane >> 4) * 8;
                const float* wp = W + (((size_t)ko * Cn + c) * 16 + ib) * 8 + j;
                afr.u.x = cvtpk(wp[0],  wp[8]);
                afr.u.y = cvtpk(wp[16], wp[24]);
                afr.u.z = cvtpk(wp[32], wp[40]);
                afr.u.w = cvtpk(wp[48], wp[56]);
            } else afr.u = make_uint4(0, 0, 0, 0);

            const int xrow = (cjb >> 2) + (lane >> 4);
            #pragma unroll
            for (int nt = 0; nt < 4; ++nt) {
                f4v acc = {0.f, 0.f, 0.f, 0.f};
                acc = __builtin_amdgcn_mfma_f32_16x16x32_bf16(afr.v, bfr[nt].v, acc, 0, 0, 0);
                const int b = nt * 16 + (lane & 15);
                const uint2 xq = *(const uint2*)(xT2 + ((size_t)xrow * 64 + b) * 4);
                float p = acc[0] * bflo(xq.x) + acc[1] * bfhi(xq.x)
                        + acc[2] * bflo(xq.y) + acc[3] * bfhi(xq.y);
                p += __shfl_xor(p, 16);           // j 0-3 + 4-7 within each c
                if (!(lane & 16)) {
                    const int c = (cjb >> 3) + (lane >> 5);
                    agr[((size_t)ko * Cn + c) * 64 + b] = p;
                }
            }
        }
    }
    if (all) grid.sync();

    // ---- P4: smax — in-place softmax over k per (b,c); one item/thread.
    if (all || phase == 4) {
        const int t = bid * 256 + tid;            // 0..131071
        float* base = agr + (size_t)(t >> 6) * 64 + (t & 63);
        float a[32];
        float mx = -1e30f;
        #pragma unroll
        for (int k = 0; k < 32; ++k) { a[k] = base[(size_t)k * (Cn * 64)]; mx = fmaxf(mx, a[k]); }
        float sum = 0.f;
        #pragma unroll
        for (int k = 0; k < 32; ++k) { a[k] = __expf(a[k] - mx); sum += a[k]; }
        const float r = 1.0f / sum;
        #pragma unroll
        for (int k = 0; k < 32; ++k) base[(size_t)k * (Cn * 64)] = a[k] * r;
    }
    if (all) grid.sync();

    // ---- P5: gemm2 — s[b,k,i] = sum_cj (cc*x)[b,cj] * W[k,cj,i] partials.
    // 512 blocks = 32 k x 16 ksplits (32 ksteps each); A-frag scaled by cc.
    if (all || phase == 5) {
        const int ko    = bid & 31;
        const int split = bid >> 5;               // 0..15
        const int ks0   = split * 32;
        const int m0    = (tid >> 6) * 16;
        const int i     = lane & 15;
        const int cq    = lane >> 4;
        const int bg    = m0 + i;

        f4v acc = {0.f, 0.f, 0.f, 0.f};
        const unsigned short* arow = xb + (size_t)bg * KJ + cq * 8;
        const float* ccp = agr + ((size_t)ko * Cn + ks0 * 4 + cq) * 64 + bg;

        for (int s = 0; s < 32; ++s) {
            const int ks = ks0 + s;
            const int c  = ks * 4 + cq;
            const uint4 au = *(const uint4*)(arow + (size_t)ks * 32);
            const float cv = ccp[s * 256];
            U16B af;
            af.u.x = cvtpk(bflo(au.x) * cv, bfhi(au.x) * cv);
            af.u.y = cvtpk(bflo(au.y) * cv, bfhi(au.y) * cv);
            af.u.z = cvtpk(bflo(au.z) * cv, bfhi(au.z) * cv);
            af.u.w = cvtpk(bflo(au.w) * cv, bfhi(au.w) * cv);
            const float* wp = W + (((size_t)ko * Cn + c) * 16 + i) * 8;
            const float4 w0 = *(const float4*)wp;
            const float4 w1 = *(const float4*)(wp + 4);
            U16B bf;
            bf.u.x = cvtpk(w0.x, w0.y); bf.u.y = cvtpk(w0.z, w0.w);
            bf.u.z = cvtpk(w1.x, w1.y); bf.u.w = cvtpk(w1.z, w1.w);
            acc = __builtin_amdgcn_mfma_f32_16x16x32_bf16(af.v, bf.v, acc, 0, 0, 0);
        }

        float* pb = part2 + (size_t)split * NOUT;
        const int col = lane & 15, rbase = (lane >> 4) * 4;
        #pragma unroll
        for (int r = 0; r < 4; ++r)
            pb[(size_t)(m0 + rbase + r) * 512 + ko * 16 + col] = acc[r];
    }
    if (all) grid.sync();

    // ---- P6: sq2 — out = squash(sum_splits part2).
    // Block bid owns items bid*16..+15 (item = 4 consecutive i); 16 subs =
    // the 16 splits, one float4 load each, LDS tree, 16 lanes finish.
    if (all || phase == 6) {
        const int itemL = tid & 15, sub = tid >> 4;   // sub 0..15
        const int item  = bid * 16 + itemL;           // 0..8191
        shB[tid] = *(const float4*)(part2 + (size_t)sub * NOUT + (size_t)item * 4);
        __syncthreads();
        if (tid < 16) {
            float4 s = make_float4(0.f, 0.f, 0.f, 0.f);
            #pragma unroll
            for (int sb = 0; sb < 16; ++sb) {
                const float4 q = shB[sb * 16 + tid];
                s.x += q.x; s.y += q.y; s.z += q.z; s.w += q.w;
            }
            float sq = (s.x * s.x + s.y * s.y) + (s.z * s.z + s.w * s.w);
            sq += __shfl_xor(sq, 1);
            sq += __shfl_xor(sq, 2);
            const float f = (sq / (1.0f + sq)) * rsqrtf(sq + EPSf);
            *(float4*)(out + (size_t)(bid * 16 + tid) * 4) =
                make_float4(s.x * f, s.y * f, s.z * f, s.w * f);
        }
    }
}

extern "C" void kernel_launch(void* const* d_in, const int* in_sizes, int n_in,
                              void* d_out, int out_size, void* d_ws, size_t ws_size,
                              hipStream_t stream)
{
    const float* x = (const float*)d_in[0];   // [64,2048,8]
    const float* W = (const float*)d_in[1];   // [32,2048,16,8]
    float* out = (float*)d_out;               // [64,32,16]
    float* wsf = (float*)d_ws;

    int phase = -1;
    void* args[] = { (void*)&x, (void*)&W, (void*)&out, (void*)&wsf, (void*)&phase };
    hipError_t err = hipLaunchCooperativeKernel((const void*)kFused, dim3(512),
                                                dim3(256), args, 0, stream);
    if (err != hipSuccess) {
        // Cooperative path unavailable: clear sticky error, run the same
        // phases as 7 regular launches (byte-identical math, proven passing).
        (void)hipGetLastError();
        for (int p = 0; p < 7; ++p)
            hipLaunchKernelGGL(kFused, dim3(512), dim3(256), 0, stream,
                               x, W, out, wsf, p);
    }
}

// Round 8
// 135.591 us; speedup vs baseline: 3.7286x; 3.7286x over previous
//
#include <hip/hip_runtime.h>

// x: [B=64, C=2048, J=8] fp32 ; W: [K=32, C=2048, I=16, J=8] fp32
// out v: [B=64, K=32, I=16] fp32
#define Cn 2048
#define EPSf 1e-7f

#define NOUT 32768            // B*K*I
#define KJ   16384            // (c,j) contraction length
#define KS1  64               // gemm1 k-splits (8 ksteps of 32 each)
#define KS2  16               // gemm2 k-splits (32 ksteps of 32 each)

typedef short bf8v __attribute__((ext_vector_type(8)));   // 8 bf16 in 4 VGPRs
typedef float f4v  __attribute__((ext_vector_type(4)));

union U16B { uint4 u; bf8v v; unsigned short h[8]; };

__device__ __forceinline__ unsigned short f2bf(float f) {
    unsigned u = __float_as_uint(f);
    u += 0x7FFF + ((u >> 16) & 1);          // round-to-nearest-even
    return (unsigned short)(u >> 16);
}
// 2 f32 -> packed bf16x2 (RNE). No builtin on gfx950; single VOP3 instr.
__device__ __forceinline__ unsigned cvtpk(float lo, float hi) {
    unsigned r;
    asm("v_cvt_pk_bf16_f32 %0, %1, %2" : "=v"(r) : "v"(lo), "v"(hi));
    return r;
}
__device__ __forceinline__ float bflo(unsigned u) { return __uint_as_float(u << 16); }
__device__ __forceinline__ float bfhi(unsigned u) { return __uint_as_float(u & 0xffff0000u); }

// ---------------------------------------------------------------------------
// 5-launch pipeline.  Cooperative fusion measured 60us/grid.sync (round 7:
// 437us, VALUBusy 2.4%) vs ~10-12us/launch gap -> stream-ordered launches win.
// ws layout (float offsets), total 21.04 MB:
//   [0 .. 4194304)        agr/cc [k][c][b] fp32 (16 MiB); part1 (KS1*NOUT =
//                         2M floats) aliases agr[0:2M] (dead before kAgrSmax).
//   [4194304 .. +524288)  xb bf16 [b][cj]
//   [4718592 .. +524288)  xT2 bf16 [cj/4][b][4]; part2 (KS2*NOUT = 512K
//                         floats) aliases xT2 exactly (xT2 dead after kAgrSmax).
//   [5242880 .. +16384)   v1f bf16 B-frags (64 KiB)
// ---------------------------------------------------------------------------

// ---- K1: gemm1 — D[b, n=(k,i)] = sum_cj x[b,cj]*W[cj,n] partials via MFMA.
// Reads x fp32 DIRECTLY (cvtpk = same RNE as the old xb path) -> no prepX dep.
// Grid 512 = 8 nstrips x 64 ksplits; 4 waves = 4 m-tiles (all of B).
__global__ __launch_bounds__(256) void kGemm1(const float* __restrict__ x,
                                              const float* __restrict__ W,
                                              float* __restrict__ part1)
{
    const int nstrip = blockIdx.x & 7;
    const int ksplit = blockIdx.x >> 3;       // 0..63
    const int ks0    = ksplit * 8;
    const int lane   = threadIdx.x & 63;
    const int m0     = (threadIdx.x >> 6) * 16;
    const int i      = lane & 15;
    const int cq     = lane >> 4;

    f4v acc[4] = {};
    const float* arow = x + (size_t)(m0 + i) * KJ + cq * 8;

    for (int s = 0; s < 8; ++s) {
        const int ks = ks0 + s;
        const float4 a0 = *(const float4*)(arow + (size_t)ks * 32);
        const float4 a1 = *(const float4*)(arow + (size_t)ks * 32 + 4);
        U16B af;
        af.u.x = cvtpk(a0.x, a0.y); af.u.y = cvtpk(a0.z, a0.w);
        af.u.z = cvtpk(a1.x, a1.y); af.u.w = cvtpk(a1.z, a1.w);
        const int c = ks * 4 + cq;
        #pragma unroll
        for (int t = 0; t < 4; ++t) {
            const int ko = nstrip * 4 + t;
            const float* wp = W + (((size_t)ko * Cn + c) * 16 + i) * 8;
            const float4 w0 = *(const float4*)wp;
            const float4 w1 = *(const float4*)(wp + 4);
            U16B bf;
            bf.u.x = cvtpk(w0.x, w0.y); bf.u.y = cvtpk(w0.z, w0.w);
            bf.u.z = cvtpk(w1.x, w1.y); bf.u.w = cvtpk(w1.z, w1.w);
            acc[t] = __builtin_amdgcn_mfma_f32_16x16x32_bf16(af.v, bf.v, acc[t], 0, 0, 0);
        }
    }
    // C/D layout: col = lane&15, row = (lane>>4)*4 + reg (verified m89/m91)
    float* pb = part1 + (size_t)ksplit * NOUT;
    const int col = lane & 15, rbase = (lane >> 4) * 4;
    #pragma unroll
    for (int t = 0; t < 4; ++t) {
        const int n = (nstrip * 4 + t) * 16 + col;
        #pragma unroll
        for (int r = 0; r < 4; ++r)
            pb[(size_t)(m0 + rbase + r) * 512 + n] = acc[t][r];
    }
}

// ---- K2: prepX + sq1.  prepX: x fp32 -> xb bf16 [b][cj] + xT2 [cj/4][b][4]
// (consumers are later launches).  sq1: v1 = squash((1/32)*sum part1) -> v1f
// bf16 B-frags.  Grid 512 x 256.
__global__ __launch_bounds__(256) void kPrepSq1(const float* __restrict__ x,
                                                const float* __restrict__ part1,
                                                unsigned short* __restrict__ xb,
                                                unsigned short* __restrict__ xT2,
                                                unsigned short* __restrict__ v1f)
{
    const int bid = blockIdx.x, tid = threadIdx.x;
    __shared__ float shA[4][65];

    {   // prepX
        const int g = bid * 256 + tid;           // 0..131071 = b*2048+c
        const float4* s = (const float4*)(x + (size_t)g * 8);
        float4 a = s[0], b4 = s[1];
        U16B o;
        o.h[0] = f2bf(a.x);  o.h[1] = f2bf(a.y);  o.h[2] = f2bf(a.z);  o.h[3] = f2bf(a.w);
        o.h[4] = f2bf(b4.x); o.h[5] = f2bf(b4.y); o.h[6] = f2bf(b4.z); o.h[7] = f2bf(b4.w);
        ((uint4*)xb)[g] = o.u;
        const int b = g >> 11, c = g & 2047;
        *(uint2*)(xT2 + ((size_t)(c * 2 + 0) * 64 + b) * 4) = make_uint2(o.u.x, o.u.y);
        *(uint2*)(xT2 + ((size_t)(c * 2 + 1) * 64 + b) * 4) = make_uint2(o.u.z, o.u.w);
    }
    {   // sq1: block owns items bid*64..+63; 4 subs x 16 splits, LDS tree.
        const int itemL = tid & 63, sub = tid >> 6;
        const int item  = bid * 64 + itemL;      // 0..32767 = ((b*32)+k)*16+i
        float s = 0.f;
        #pragma unroll 4
        for (int g = 0; g < 16; ++g)
            s += part1[(size_t)(sub * 16 + g) * NOUT + item];
        shA[sub][itemL] = s;
        __syncthreads();
        if (tid < 64) {
            float s2 = (shA[0][tid] + shA[1][tid]) + (shA[2][tid] + shA[3][tid]);
            s2 *= (1.0f / 32.0f);                // softmax(0) over k = 1/32
            float sq = s2 * s2;                  // reduce over the 16 i's
            sq += __shfl_xor(sq, 1);
            sq += __shfl_xor(sq, 2);
            sq += __shfl_xor(sq, 4);
            sq += __shfl_xor(sq, 8);
            const float f = (sq / (1.0f + sq)) * rsqrtf(sq + EPSf);
            const float v = s2 * f;
            const int it = bid * 64 + tid;
            const int b = it >> 9, k = (it >> 4) & 31, ii = it & 15;
            // B-frag slot: lane = (i>>3)*16 + (b&15)
            const int pos = ((k * 4 + (b >> 4)) * 32 + (ii >> 3) * 16 + (b & 15)) * 8 + (ii & 7);
            v1f[pos] = f2bf(v);
        }
    }
}

// ---- K3: agr + smax fused.  Block = 8 c (64 cj, wave w -> m-tile w), loops
// over ALL 32 k, staging p[c][b][k] in LDS (67.6 KB, +1-pad), then in-block
// softmax over k and write cc[k][c][b].  Deletes the kSmax launch AND a
// 16MB+16MB agr round-trip.  Grid 256 x 256.
__global__ __launch_bounds__(256) void kAgrSmax(const float* __restrict__ W,
                                                const unsigned short* __restrict__ v1f,
                                                const unsigned short* __restrict__ xT2,
                                                float* __restrict__ cc)
{
    const int cgi  = blockIdx.x;               // 0..255: c-group of 8 c
    const int tid  = threadIdx.x;
    const int lane = tid & 63;
    const int w    = tid >> 6;

    __shared__ float lds_p[8][64][33];

    const int cj0 = cgi * 64 + w * 16;         // this wave's m-tile
    // xT2 reads are k-invariant: preload the 4 nt quads.
    const int xrow = (cj0 >> 2) + (lane >> 4);
    uint2 xq[4];
    #pragma unroll
    for (int nt = 0; nt < 4; ++nt) {
        const int b = nt * 16 + (lane & 15);
        xq[nt] = *(const uint2*)(xT2 + ((size_t)xrow * 64 + b) * 4);
    }

    for (int ko = 0; ko < 32; ++ko) {
        U16B afr;                              // A-frag: m=cj, kdim=i (pad>=16)
        U16B bfr[4];
        if (lane < 32) {
            const int cj = cj0 + (lane & 15);
            const int c = cj >> 3, j = cj & 7;
            const int ib = (lane >> 4) * 8;
            const float* wp = W + (((size_t)ko * Cn + c) * 16 + ib) * 8 + j;
            afr.u.x = cvtpk(wp[0],  wp[8]);
            afr.u.y = cvtpk(wp[16], wp[24]);
            afr.u.z = cvtpk(wp[32], wp[40]);
            afr.u.w = cvtpk(wp[48], wp[56]);
            #pragma unroll
            for (int nt = 0; nt < 4; ++nt)
                bfr[nt].u = *(const uint4*)(v1f + ((size_t)(ko * 4 + nt) * 32 + lane) * 8);
        } else {
            afr.u = make_uint4(0, 0, 0, 0);
            #pragma unroll
            for (int nt = 0; nt < 4; ++nt) bfr[nt].u = make_uint4(0, 0, 0, 0);
        }

        #pragma unroll
        for (int nt = 0; nt < 4; ++nt) {
            f4v acc = {0.f, 0.f, 0.f, 0.f};
            acc = __builtin_amdgcn_mfma_f32_16x16x32_bf16(afr.v, bfr[nt].v, acc, 0, 0, 0);
            float p = acc[0] * bflo(xq[nt].x) + acc[1] * bfhi(xq[nt].x)
                    + acc[2] * bflo(xq[nt].y) + acc[3] * bfhi(xq[nt].y);
            p += __shfl_xor(p, 16);            // j 0-3 + 4-7 within each c
            if (!(lane & 16)) {                // g=0 -> c0, g=2 -> c1 of the mt
                const int cl = w * 2 + (lane >> 5);
                const int b  = nt * 16 + (lane & 15);
                lds_p[cl][b][ko] = p;
            }
        }
    }
    __syncthreads();

    // softmax over k per (c,b): 512 items, 2 per thread.
    #pragma unroll
    for (int rep = 0; rep < 2; ++rep) {
        const int s  = rep * 256 + tid;        // 0..511
        const int cl = s >> 6, b = s & 63;
        float a[32];
        float mx = -1e30f;
        #pragma unroll
        for (int k = 0; k < 32; ++k) { a[k] = lds_p[cl][b][k]; mx = fmaxf(mx, a[k]); }
        float sum = 0.f;
        #pragma unroll
        for (int k = 0; k < 32; ++k) { a[k] = __expf(a[k] - mx); sum += a[k]; }
        const float r = 1.0f / sum;
        const int c = cgi * 8 + cl;
        #pragma unroll
        for (int k = 0; k < 32; ++k)
            cc[((size_t)k * Cn + c) * 64 + b] = a[k] * r;
    }
}

// ---- K4: gemm2 — s[b,k,i] = sum_cj (cc*x)[b,cj] * W[k,cj,i] partials.
// Grid 512 = 32 k x 16 ksplits (32 ksteps each); A-frag scaled by cc.
__global__ __launch_bounds__(256) void kGemm2(const unsigned short* __restrict__ xb,
                                              const float* __restrict__ W,
                                              const float* __restrict__ cc,
                                              float* __restrict__ part2)
{
    const int ko    = blockIdx.x & 31;
    const int split = blockIdx.x >> 5;        // 0..15
    const int ks0   = split * 32;
    const int lane  = threadIdx.x & 63;
    const int m0    = (threadIdx.x >> 6) * 16;
    const int i     = lane & 15;
    const int cq    = lane >> 4;
    const int bg    = m0 + i;

    f4v acc = {0.f, 0.f, 0.f, 0.f};
    const unsigned short* arow = xb + (size_t)bg * KJ + cq * 8;
    const float* ccp = cc + ((size_t)ko * Cn + ks0 * 4 + cq) * 64 + bg;

    for (int s = 0; s < 32; ++s) {
        const int ks = ks0 + s;
        const int c  = ks * 4 + cq;
        const uint4 au = *(const uint4*)(arow + (size_t)ks * 32);
        const float cv = ccp[s * 256];
        U16B af;
        af.u.x = cvtpk(bflo(au.x) * cv, bfhi(au.x) * cv);
        af.u.y = cvtpk(bflo(au.y) * cv, bfhi(au.y) * cv);
        af.u.z = cvtpk(bflo(au.z) * cv, bfhi(au.z) * cv);
        af.u.w = cvtpk(bflo(au.w) * cv, bfhi(au.w) * cv);
        const float* wp = W + (((size_t)ko * Cn + c) * 16 + i) * 8;
        const float4 w0 = *(const float4*)wp;
        const float4 w1 = *(const float4*)(wp + 4);
        U16B bf;
        bf.u.x = cvtpk(w0.x, w0.y); bf.u.y = cvtpk(w0.z, w0.w);
        bf.u.z = cvtpk(w1.x, w1.y); bf.u.w = cvtpk(w1.z, w1.w);
        acc = __builtin_amdgcn_mfma_f32_16x16x32_bf16(af.v, bf.v, acc, 0, 0, 0);
    }

    float* pb = part2 + (size_t)split * NOUT;
    const int col = lane & 15, rbase = (lane >> 4) * 4;
    #pragma unroll
    for (int r = 0; r < 4; ++r)
        pb[(size_t)(m0 + rbase + r) * 512 + ko * 16 + col] = acc[r];
}

// ---- K5: sq2 — out = squash(sum_splits part2).  Grid 512; block owns 16
// items (4 consecutive i); 16 subs = the 16 splits, LDS tree, 16 lanes finish.
__global__ __launch_bounds__(256) void kSq2(const float* __restrict__ part2,
                                            float* __restrict__ out)
{
    const int bid = blockIdx.x, tid = threadIdx.x;
    __shared__ float4 shB[256];
    const int itemL = tid & 15, sub = tid >> 4;   // sub 0..15
    const int item  = bid * 16 + itemL;           // 0..8191
    shB[tid] = *(const float4*)(part2 + (size_t)sub * NOUT + (size_t)item * 4);
    __syncthreads();
    if (tid < 16) {
        float4 s = make_float4(0.f, 0.f, 0.f, 0.f);
        #pragma unroll
        for (int sb = 0; sb < 16; ++sb) {
            const float4 q = shB[sb * 16 + tid];
            s.x += q.x; s.y += q.y; s.z += q.z; s.w += q.w;
        }
        float sq = (s.x * s.x + s.y * s.y) + (s.z * s.z + s.w * s.w);
        sq += __shfl_xor(sq, 1);
        sq += __shfl_xor(sq, 2);
        const float f = (sq / (1.0f + sq)) * rsqrtf(sq + EPSf);
        *(float4*)(out + (size_t)(bid * 16 + tid) * 4) =
            make_float4(s.x * f, s.y * f, s.z * f, s.w * f);
    }
}

extern "C" void kernel_launch(void* const* d_in, const int* in_sizes, int n_in,
                              void* d_out, int out_size, void* d_ws, size_t ws_size,
                              hipStream_t stream)
{
    const float* x = (const float*)d_in[0];   // [64,2048,8]
    const float* W = (const float*)d_in[1];   // [32,2048,16,8]
    float* out = (float*)d_out;               // [64,32,16]
    float* wsf = (float*)d_ws;

    float*          agr   = wsf;
    float*          part1 = wsf;
    unsigned short* xb    = (unsigned short*)(wsf + 4194304);
    unsigned short* xT2   = (unsigned short*)(wsf + 4718592);
    float*          part2 = wsf + 4718592;
    unsigned short* v1f   = (unsigned short*)(wsf + 5242880);

    kGemm1  <<<512, 256, 0, stream>>>(x, W, part1);
    kPrepSq1<<<512, 256, 0, stream>>>(x, part1, xb, xT2, v1f);
    kAgrSmax<<<256, 256, 0, stream>>>(W, v1f, xT2, agr);
    kGemm2  <<<512, 256, 0, stream>>>(xb, W, agr, part2);
    kSq2    <<<512, 256, 0, stream>>>(part2, out);
}

// Round 13
// 122.961 us; speedup vs baseline: 4.1116x; 1.1027x over previous
//
#include <hip/hip_runtime.h>

// x: [B=64, C=2048, J=8] fp32 ; W: [K=32, C=2048, I=16, J=8] fp32
// out v: [B=64, K=32, I=16] fp32
#define Cn 2048
#define EPSf 1e-7f

#define NOUT 32768            // B*K*I
#define KJ   16384            // (c,j) contraction length
#define KS1  64               // gemm1 k-splits (8 ksteps of 32 each)
#define KS2  16               // gemm2 k-splits (32 ksteps of 32 each)

typedef short bf8v __attribute__((ext_vector_type(8)));   // 8 bf16 in 4 VGPRs
typedef float f4v  __attribute__((ext_vector_type(4)));

union U16B { uint4 u; bf8v v; unsigned short h[8]; };

__device__ __forceinline__ unsigned short f2bf(float f) {
    unsigned u = __float_as_uint(f);
    u += 0x7FFF + ((u >> 16) & 1);          // round-to-nearest-even
    return (unsigned short)(u >> 16);
}
// 2 f32 -> packed bf16x2 (RNE). No builtin on gfx950; single VOP3 instr.
__device__ __forceinline__ unsigned cvtpk(float lo, float hi) {
    unsigned r;
    asm("v_cvt_pk_bf16_f32 %0, %1, %2" : "=v"(r) : "v"(lo), "v"(hi));
    return r;
}
__device__ __forceinline__ float bflo(unsigned u) { return __uint_as_float(u << 16); }
__device__ __forceinline__ float bfhi(unsigned u) { return __uint_as_float(u & 0xffff0000u); }

// ---------------------------------------------------------------------------
// 5-launch pipeline.  Round-8 post-mortem: kAgrSmax at 256 blocks/67.6KB LDS
// = 1 wave/SIMD (zero latency hiding) ate the fusion savings.  This round:
// same math, re-tiled to 1024 blocks x 2c, LDS 16.9KB -> 16 waves/CU.
// ws layout (float offsets), total 21.04 MB:
//   [0 .. 4194304)        agr/cc [k][c][b] fp32 (16 MiB); part1 (KS1*NOUT =
//                         2M floats) aliases agr[0:2M] (dead before kAgrSmax).
//   [4194304 .. +524288)  xb bf16 [b][cj]
//   [4718592 .. +524288)  xT2 bf16 [cj/4][b][4]; part2 (KS2*NOUT = 512K
//                         floats) aliases xT2 exactly (xT2 dead after kAgrSmax).
//   [5242880 .. +16384)   v1f bf16 B-frags (64 KiB)
// ---------------------------------------------------------------------------

// ---- K1: gemm1 — D[b, n=(k,i)] = sum_cj x[b,cj]*W[cj,n] partials via MFMA.
// Reads x fp32 DIRECTLY (cvtpk = same RNE as the old xb path) -> no prepX dep.
// Grid 512 = 8 nstrips x 64 ksplits; 4 waves = 4 m-tiles (all of B).
__global__ __launch_bounds__(256) void kGemm1(const float* __restrict__ x,
                                              const float* __restrict__ W,
                                              float* __restrict__ part1)
{
    const int nstrip = blockIdx.x & 7;
    const int ksplit = blockIdx.x >> 3;       // 0..63
    const int ks0    = ksplit * 8;
    const int lane   = threadIdx.x & 63;
    const int m0     = (threadIdx.x >> 6) * 16;
    const int i      = lane & 15;
    const int cq     = lane >> 4;

    f4v acc[4] = {};
    const float* arow = x + (size_t)(m0 + i) * KJ + cq * 8;

    for (int s = 0; s < 8; ++s) {
        const int ks = ks0 + s;
        const float4 a0 = *(const float4*)(arow + (size_t)ks * 32);
        const float4 a1 = *(const float4*)(arow + (size_t)ks * 32 + 4);
        U16B af;
        af.u.x = cvtpk(a0.x, a0.y); af.u.y = cvtpk(a0.z, a0.w);
        af.u.z = cvtpk(a1.x, a1.y); af.u.w = cvtpk(a1.z, a1.w);
        const int c = ks * 4 + cq;
        #pragma unroll
        for (int t = 0; t < 4; ++t) {
            const int ko = nstrip * 4 + t;
            const float* wp = W + (((size_t)ko * Cn + c) * 16 + i) * 8;
            const float4 w0 = *(const float4*)wp;
            const float4 w1 = *(const float4*)(wp + 4);
            U16B bf;
            bf.u.x = cvtpk(w0.x, w0.y); bf.u.y = cvtpk(w0.z, w0.w);
            bf.u.z = cvtpk(w1.x, w1.y); bf.u.w = cvtpk(w1.z, w1.w);
            acc[t] = __builtin_amdgcn_mfma_f32_16x16x32_bf16(af.v, bf.v, acc[t], 0, 0, 0);
        }
    }
    // C/D layout: col = lane&15, row = (lane>>4)*4 + reg (verified m89/m91)
    float* pb = part1 + (size_t)ksplit * NOUT;
    const int col = lane & 15, rbase = (lane >> 4) * 4;
    #pragma unroll
    for (int t = 0; t < 4; ++t) {
        const int n = (nstrip * 4 + t) * 16 + col;
        #pragma unroll
        for (int r = 0; r < 4; ++r)
            pb[(size_t)(m0 + rbase + r) * 512 + n] = acc[t][r];
    }
}

// ---- K2: prepX + sq1.  prepX: x fp32 -> xb bf16 [b][cj] + xT2 [cj/4][b][4]
// (consumers are later launches).  sq1: v1 = squash((1/32)*sum part1) -> v1f
// bf16 B-frags.  Grid 512 x 256.
__global__ __launch_bounds__(256) void kPrepSq1(const float* __restrict__ x,
                                                const float* __restrict__ part1,
                                                unsigned short* __restrict__ xb,
                                                unsigned short* __restrict__ xT2,
                                                unsigned short* __restrict__ v1f)
{
    const int bid = blockIdx.x, tid = threadIdx.x;
    __shared__ float shA[4][65];

    {   // prepX
        const int g = bid * 256 + tid;           // 0..131071 = b*2048+c
        const float4* s = (const float4*)(x + (size_t)g * 8);
        float4 a = s[0], b4 = s[1];
        U16B o;
        o.h[0] = f2bf(a.x);  o.h[1] = f2bf(a.y);  o.h[2] = f2bf(a.z);  o.h[3] = f2bf(a.w);
        o.h[4] = f2bf(b4.x); o.h[5] = f2bf(b4.y); o.h[6] = f2bf(b4.z); o.h[7] = f2bf(b4.w);
        ((uint4*)xb)[g] = o.u;
        const int b = g >> 11, c = g & 2047;
        *(uint2*)(xT2 + ((size_t)(c * 2 + 0) * 64 + b) * 4) = make_uint2(o.u.x, o.u.y);
        *(uint2*)(xT2 + ((size_t)(c * 2 + 1) * 64 + b) * 4) = make_uint2(o.u.z, o.u.w);
    }
    {   // sq1: block owns items bid*64..+63; 4 subs x 16 splits, LDS tree.
        const int itemL = tid & 63, sub = tid >> 6;
        const int item  = bid * 64 + itemL;      // 0..32767 = ((b*32)+k)*16+i
        float s = 0.f;
        #pragma unroll 4
        for (int g = 0; g < 16; ++g)
            s += part1[(size_t)(sub * 16 + g) * NOUT + item];
        shA[sub][itemL] = s;
        __syncthreads();
        if (tid < 64) {
            float s2 = (shA[0][tid] + shA[1][tid]) + (shA[2][tid] + shA[3][tid]);
            s2 *= (1.0f / 32.0f);                // softmax(0) over k = 1/32
            float sq = s2 * s2;                  // reduce over the 16 i's
            sq += __shfl_xor(sq, 1);
            sq += __shfl_xor(sq, 2);
            sq += __shfl_xor(sq, 4);
            sq += __shfl_xor(sq, 8);
            const float f = (sq / (1.0f + sq)) * rsqrtf(sq + EPSf);
            const float v = s2 * f;
            const int it = bid * 64 + tid;
            const int b = it >> 9, k = (it >> 4) & 31, ii = it & 15;
            // B-frag slot: lane = (i>>3)*16 + (b&15)
            const int pos = ((k * 4 + (b >> 4)) * 32 + (ii >> 3) * 16 + (b & 15)) * 8 + (ii & 7);
            v1f[pos] = f2bf(v);
        }
    }
}

// ---- K3: agr + smax fused (v2, occupancy-fixed).  Block = 2 c (one 16-cj
// m-tile); the 4 waves split the 32-ko range (8 each) and stage p[c][b][k]
// in LDS (16.9 KB -> 4 blocks/CU, 16 waves/CU; round-8's 67.6 KB gave
// 1 wave/SIMD and was latency-bound).  Then in-block softmax over k, write
// cc[k][c][b].  Grid 1024 x 256.
__global__ __launch_bounds__(256) void kAgrSmax(const float* __restrict__ W,
                                                const unsigned short* __restrict__ v1f,
                                                const unsigned short* __restrict__ xT2,
                                                float* __restrict__ cc)
{
    const int cgi  = blockIdx.x;               // 0..1023: c-group of 2 c
    const int tid  = threadIdx.x;
    const int lane = tid & 63;
    const int w    = tid >> 6;                 // wave -> ko slice

    __shared__ float lds_p[2][64][33];

    const int cj0 = cgi * 16;                  // the block's single m-tile
    const int ko0 = w * 8;

    // xT2 reads are k-invariant: preload the 4 nt quads.
    const int xrow = (cj0 >> 2) + (lane >> 4);
    uint2 xq[4];
    #pragma unroll
    for (int nt = 0; nt < 4; ++nt) {
        const int b = nt * 16 + (lane & 15);
        xq[nt] = *(const uint2*)(xT2 + ((size_t)xrow * 64 + b) * 4);
    }

    for (int ko = ko0; ko < ko0 + 8; ++ko) {
        U16B afr;                              // A-frag: m=cj, kdim=i (pad>=16)
        U16B bfr[4];
        if (lane < 32) {
            const int cj = cj0 + (lane & 15);
            const int c = cj >> 3, j = cj & 7;
            const int ib = (lane >> 4) * 8;
            const float* wp = W + (((size_t)ko * Cn + c) * 16 + ib) * 8 + j;
            afr.u.x = cvtpk(wp[0],  wp[8]);
            afr.u.y = cvtpk(wp[16], wp[24]);
            afr.u.z = cvtpk(wp[32], wp[40]);
            afr.u.w = cvtpk(wp[48], wp[56]);
            #pragma unroll
            for (int nt = 0; nt < 4; ++nt)
                bfr[nt].u = *(const uint4*)(v1f + ((size_t)(ko * 4 + nt) * 32 + lane) * 8);
        } else {
            afr.u = make_uint4(0, 0, 0, 0);
            #pragma unroll
            for (int nt = 0; nt < 4; ++nt) bfr[nt].u = make_uint4(0, 0, 0, 0);
        }

        #pragma unroll
        for (int nt = 0; nt < 4; ++nt) {
            f4v acc = {0.f, 0.f, 0.f, 0.f};
            acc = __builtin_amdgcn_mfma_f32_16x16x32_bf16(afr.v, bfr[nt].v, acc, 0, 0, 0);
            float p = acc[0] * bflo(xq[nt].x) + acc[1] * bfhi(xq[nt].x)
                    + acc[2] * bflo(xq[nt].y) + acc[3] * bfhi(xq[nt].y);
            p += __shfl_xor(p, 16);            // j 0-3 + 4-7 within each c
            if (!(lane & 16)) {                // g=0 -> c0, g=2 -> c1
                const int cl = lane >> 5;
                const int b  = nt * 16 + (lane & 15);
                lds_p[cl][b][ko] = p;
            }
        }
    }
    __syncthreads();

    // softmax over k per (c,b): 128 items, 1 per thread (tid<128).
    if (tid < 128) {
        const int cl = tid >> 6, b = tid & 63;
        float a[32];
        float mx = -1e30f;
        #pragma unroll
        for (int k = 0; k < 32; ++k) { a[k] = lds_p[cl][b][k]; mx = fmaxf(mx, a[k]); }
        float sum = 0.f;
        #pragma unroll
        for (int k = 0; k < 32; ++k) { a[k] = __expf(a[k] - mx); sum += a[k]; }
        const float r = 1.0f / sum;
        const int c = cgi * 2 + cl;
        #pragma unroll
        for (int k = 0; k < 32; ++k)
            cc[((size_t)k * Cn + c) * 64 + b] = a[k] * r;
    }
}

// ---- K4: gemm2 — s[b,k,i] = sum_cj (cc*x)[b,cj] * W[k,cj,i] partials.
// Grid 512 = 32 k x 16 ksplits (32 ksteps each); A-frag scaled by cc.
__global__ __launch_bounds__(256) void kGemm2(const unsigned short* __restrict__ xb,
                                              const float* __restrict__ W,
                                              const float* __restrict__ cc,
                                              float* __restrict__ part2)
{
    const int ko    = blockIdx.x & 31;
    const int split = blockIdx.x >> 5;        // 0..15
    const int ks0   = split * 32;
    const int lane  = threadIdx.x & 63;
    const int m0    = (threadIdx.x >> 6) * 16;
    const int i     = lane & 15;
    const int cq    = lane >> 4;
    const int bg    = m0 + i;

    f4v acc = {0.f, 0.f, 0.f, 0.f};
    const unsigned short* arow = xb + (size_t)bg * KJ + cq * 8;
    const float* ccp = cc + ((size_t)ko * Cn + ks0 * 4 + cq) * 64 + bg;

    for (int s = 0; s < 32; ++s) {
        const int ks = ks0 + s;
        const int c  = ks * 4 + cq;
        const uint4 au = *(const uint4*)(arow + (size_t)ks * 32);
        const float cv = ccp[s * 256];
        U16B af;
        af.u.x = cvtpk(bflo(au.x) * cv, bfhi(au.x) * cv);
        af.u.y = cvtpk(bflo(au.y) * cv, bfhi(au.y) * cv);
        af.u.z = cvtpk(bflo(au.z) * cv, bfhi(au.z) * cv);
        af.u.w = cvtpk(bflo(au.w) * cv, bfhi(au.w) * cv);
        const float* wp = W + (((size_t)ko * Cn + c) * 16 + i) * 8;
        const float4 w0 = *(const float4*)wp;
        const float4 w1 = *(const float4*)(wp + 4);
        U16B bf;
        bf.u.x = cvtpk(w0.x, w0.y); bf.u.y = cvtpk(w0.z, w0.w);
        bf.u.z = cvtpk(w1.x, w1.y); bf.u.w = cvtpk(w1.z, w1.w);
        acc = __builtin_amdgcn_mfma_f32_16x16x32_bf16(af.v, bf.v, acc, 0, 0, 0);
    }

    float* pb = part2 + (size_t)split * NOUT;
    const int col = lane & 15, rbase = (lane >> 4) * 4;
    #pragma unroll
    for (int r = 0; r < 4; ++r)
        pb[(size_t)(m0 + rbase + r) * 512 + ko * 16 + col] = acc[r];
}

// ---- K5: sq2 — out = squash(sum_splits part2).  Grid 512; block owns 16
// items (4 consecutive i); 16 subs = the 16 splits, LDS tree, 16 lanes finish.
__global__ __launch_bounds__(256) void kSq2(const float* __restrict__ part2,
                                            float* __restrict__ out)
{
    const int bid = blockIdx.x, tid = threadIdx.x;
    __shared__ float4 shB[256];
    const int itemL = tid & 15, sub = tid >> 4;   // sub 0..15
    const int item  = bid * 16 + itemL;           // 0..8191
    shB[tid] = *(const float4*)(part2 + (size_t)sub * NOUT + (size_t)item * 4);
    __syncthreads();
    if (tid < 16) {
        float4 s = make_float4(0.f, 0.f, 0.f, 0.f);
        #pragma unroll
        for (int sb = 0; sb < 16; ++sb) {
            const float4 q = shB[sb * 16 + tid];
            s.x += q.x; s.y += q.y; s.z += q.z; s.w += q.w;
        }
        float sq = (s.x * s.x + s.y * s.y) + (s.z * s.z + s.w * s.w);
        sq += __shfl_xor(sq, 1);
        sq += __shfl_xor(sq, 2);
        const float f = (sq / (1.0f + sq)) * rsqrtf(sq + EPSf);
        *(float4*)(out + (size_t)(bid * 16 + tid) * 4) =
            make_float4(s.x * f, s.y * f, s.z * f, s.w * f);
    }
}

extern "C" void kernel_launch(void* const* d_in, const int* in_sizes, int n_in,
                              void* d_out, int out_size, void* d_ws, size_t ws_size,
                              hipStream_t stream)
{
    const float* x = (const float*)d_in[0];   // [64,2048,8]
    const float* W = (const float*)d_in[1];   // [32,2048,16,8]
    float* out = (float*)d_out;               // [64,32,16]
    float* wsf = (float*)d_ws;

    float*          agr   = wsf;
    float*          part1 = wsf;
    unsigned short* xb    = (unsigned short*)(wsf + 4194304);
    unsigned short* xT2   = (unsigned short*)(wsf + 4718592);
    float*          part2 = wsf + 4718592;
    unsigned short* v1f   = (unsigned short*)(wsf + 5242880);

    kGemm1  <<<512,  256, 0, stream>>>(x, W, part1);
    kPrepSq1<<<512,  256, 0, stream>>>(x, part1, xb, xT2, v1f);
    kAgrSmax<<<1024, 256, 0, stream>>>(W, v1f, xT2, agr);
    kGemm2  <<<512,  256, 0, stream>>>(xb, W, agr, part2);
    kSq2    <<<512,  256, 0, stream>>>(part2, out);
}

// Round 16
// 119.688 us; speedup vs baseline: 4.2240x; 1.0273x over previous
//
#include <hip/hip_runtime.h>

// x: [B=64, C=2048, J=8] fp32 ; W: [K=32, C=2048, I=16, J=8] fp32
// out v: [B=64, K=32, I=16] fp32
#define Cn 2048
#define EPSf 1e-7f

#define NOUT 32768            // B*K*I
#define KJ   16384            // (c,j) contraction length
#define KS1  64               // gemm1 k-splits (8 ksteps of 32 each)
#define KS2  16               // gemm2 k-splits (32 ksteps of 32 each)

typedef short bf8v __attribute__((ext_vector_type(8)));   // 8 bf16 in 4 VGPRs
typedef float f4v  __attribute__((ext_vector_type(4)));

union U16B { uint4 u; bf8v v; unsigned short h[8]; };

__device__ __forceinline__ unsigned short f2bf(float f) {
    unsigned u = __float_as_uint(f);
    u += 0x7FFF + ((u >> 16) & 1);          // round-to-nearest-even
    return (unsigned short)(u >> 16);
}
// 2 f32 -> packed bf16x2 (RNE). No builtin on gfx950; single VOP3 instr.
__device__ __forceinline__ unsigned cvtpk(float lo, float hi) {
    unsigned r;
    asm("v_cvt_pk_bf16_f32 %0, %1, %2" : "=v"(r) : "v"(lo), "v"(hi));
    return r;
}
__device__ __forceinline__ float bflo(unsigned u) { return __uint_as_float(u << 16); }
__device__ __forceinline__ float bfhi(unsigned u) { return __uint_as_float(u & 0xffff0000u); }
__device__ __forceinline__ float bf1(unsigned short h) { return __uint_as_float((unsigned)h << 16); }

// ---------------------------------------------------------------------------
// 5-launch pipeline, round 14: stop re-reading W fp32 3x.  K1 emits wb (bf16
// W image, 16 MB — identical RNE bits it already computes) + xb/xT2 as
// byproducts; K3/K4 read wb (16 MB each, was 32); cc stored bf16 (8 MB, was
// 16).  Net traffic 156 -> ~130 MB.  The 256 MiB harness fill (round 13
// counters) established ws_size ~256 MiB, so the 28 MiB layout fits.
// ws layout (float offsets), 28.03 MiB total:
//   [0 .. 4194304)        wb bf16 [k][c][i][j]  (16 MiB, K1 -> K3,K4)
//   [4194304 .. +2097152) part1 fp32 (8 MiB, K1 -> K2);
//                         ccb bf16 [k][c][b] ALIASES it (K3 -> K4; part1 dead)
//   [6291456 .. +524288)  xb bf16 [b][cj]       (2 MiB, K1 -> K4)
//   [6815744 .. +524288)  xT2 bf16 [cj/4][b][4] (2 MiB, K1 -> K3);
//                         part2 fp32 ALIASES it exactly (K4 -> K5)
//   [7340032 .. +8192)    v1f bf16 B-frags      (64 KiB, K2 -> K3)
// ---------------------------------------------------------------------------

// ---- K1: gemm1 + W/x bf16 emission.  D[b, n=(k,i)] = sum_cj x*W partials.
// Grid 512 = 8 nstrips x 64 ksplits; 4 waves = 4 m-tiles (all of B).
// Every (ko,c,i,j) B-frag is computed exactly once across the grid -> wb
// store is duplicate-free.  nstrip==0 blocks also cover every (b,cj) A-frag
// exactly once -> they emit xb/xT2 (what kPrepSq1's prepX half did).
__global__ __launch_bounds__(256) void kGemm1(const float* __restrict__ x,
                                              const float* __restrict__ W,
                                              float* __restrict__ part1,
                                              unsigned short* __restrict__ wb,
                                              unsigned short* __restrict__ xb,
                                              unsigned short* __restrict__ xT2)
{
    const int nstrip = blockIdx.x & 7;
    const int ksplit = blockIdx.x >> 3;       // 0..63
    const int ks0    = ksplit * 8;
    const int lane   = threadIdx.x & 63;
    const int m0     = (threadIdx.x >> 6) * 16;
    const int i      = lane & 15;
    const int cq     = lane >> 4;

    f4v acc[4] = {};
    const float* arow = x + (size_t)(m0 + i) * KJ + cq * 8;

    for (int s = 0; s < 8; ++s) {
        const int ks = ks0 + s;
        const float4 a0 = *(const float4*)(arow + (size_t)ks * 32);
        const float4 a1 = *(const float4*)(arow + (size_t)ks * 32 + 4);
        U16B af;
        af.u.x = cvtpk(a0.x, a0.y); af.u.y = cvtpk(a0.z, a0.w);
        af.u.z = cvtpk(a1.x, a1.y); af.u.w = cvtpk(a1.z, a1.w);
        const int c = ks * 4 + cq;
        if (nstrip == 0) {                    // emit x bf16 (unique per grid)
            const int b   = m0 + i;
            const int cj0 = ks * 32 + cq * 8;
            *(uint4*)(xb + (size_t)b * KJ + cj0) = af.u;
            *(uint2*)(xT2 + ((size_t)((cj0 >> 2) + 0) * 64 + b) * 4) = make_uint2(af.u.x, af.u.y);
            *(uint2*)(xT2 + ((size_t)((cj0 >> 2) + 1) * 64 + b) * 4) = make_uint2(af.u.z, af.u.w);
        }
        #pragma unroll
        for (int t = 0; t < 4; ++t) {
            const int ko = nstrip * 4 + t;
            const float* wp = W + (((size_t)ko * Cn + c) * 16 + i) * 8;
            const float4 w0 = *(const float4*)wp;
            const float4 w1 = *(const float4*)(wp + 4);
            U16B bf;
            bf.u.x = cvtpk(w0.x, w0.y); bf.u.y = cvtpk(w0.z, w0.w);
            bf.u.z = cvtpk(w1.x, w1.y); bf.u.w = cvtpk(w1.z, w1.w);
            *(uint4*)(wb + (((size_t)ko * Cn + c) * 16 + i) * 8) = bf.u;  // W bf16 image
            acc[t] = __builtin_amdgcn_mfma_f32_16x16x32_bf16(af.v, bf.v, acc[t], 0, 0, 0);
        }
    }
    // C/D layout: col = lane&15, row = (lane>>4)*4 + reg (verified m89/m91)
    float* pb = part1 + (size_t)ksplit * NOUT;
    const int col = lane & 15, rbase = (lane >> 4) * 4;
    #pragma unroll
    for (int t = 0; t < 4; ++t) {
        const int n = (nstrip * 4 + t) * 16 + col;
        #pragma unroll
        for (int r = 0; r < 4; ++r)
            pb[(size_t)(m0 + rbase + r) * 512 + n] = acc[t][r];
    }
}

// ---- K2: sq1 — v1 = squash((1/32)*sum_splits part1) -> v1f bf16 B-frags.
// Grid 512 x 256; block owns items bid*64..+63; 4 subs x 16 splits, LDS tree.
__global__ __launch_bounds__(256) void kSq1(const float* __restrict__ part1,
                                            unsigned short* __restrict__ v1f)
{
    const int bid = blockIdx.x, tid = threadIdx.x;
    __shared__ float shA[4][65];
    const int itemL = tid & 63, sub = tid >> 6;
    const int item  = bid * 64 + itemL;      // 0..32767 = ((b*32)+k)*16+i
    float s = 0.f;
    #pragma unroll 4
    for (int g = 0; g < 16; ++g)
        s += part1[(size_t)(sub * 16 + g) * NOUT + item];
    shA[sub][itemL] = s;
    __syncthreads();
    if (tid < 64) {
        float s2 = (shA[0][tid] + shA[1][tid]) + (shA[2][tid] + shA[3][tid]);
        s2 *= (1.0f / 32.0f);                // softmax(0) over k = 1/32
        float sq = s2 * s2;                  // reduce over the 16 i's
        sq += __shfl_xor(sq, 1);
        sq += __shfl_xor(sq, 2);
        sq += __shfl_xor(sq, 4);
        sq += __shfl_xor(sq, 8);
        const float f = (sq / (1.0f + sq)) * rsqrtf(sq + EPSf);
        const float v = s2 * f;
        const int it = bid * 64 + tid;
        const int b = it >> 9, k = (it >> 4) & 31, ii = it & 15;
        // B-frag slot: lane = (i>>3)*16 + (b&15)
        const int pos = ((k * 4 + (b >> 4)) * 32 + (ii >> 3) * 16 + (b & 15)) * 8 + (ii & 7);
        v1f[pos] = f2bf(v);
    }
}

// ---- K3: agr + smax fused.  Block = 2 c (one 16-cj m-tile); 4 waves split
// the 32-ko range (8 each), stage p[c][b][k] in LDS (16.9 KB, 16 waves/CU),
// in-block softmax over k, write cc bf16.  W read from wb (16 MB, was 32).
// Grid 1024 x 256.
__global__ __launch_bounds__(256) void kAgrSmax(const unsigned short* __restrict__ wb,
                                                const unsigned short* __restrict__ v1f,
                                                const unsigned short* __restrict__ xT2,
                                                unsigned short* __restrict__ ccb)
{
    const int cgi  = blockIdx.x;               // 0..1023: c-group of 2 c
    const int tid  = threadIdx.x;
    const int lane = tid & 63;
    const int w    = tid >> 6;                 // wave -> ko slice

    __shared__ float lds_p[2][64][33];

    const int cj0 = cgi * 16;                  // the block's single m-tile
    const int ko0 = w * 8;

    // xT2 reads are k-invariant: preload the 4 nt quads.
    const int xrow = (cj0 >> 2) + (lane >> 4);
    uint2 xq[4];
    #pragma unroll
    for (int nt = 0; nt < 4; ++nt) {
        const int b = nt * 16 + (lane & 15);
        xq[nt] = *(const uint2*)(xT2 + ((size_t)xrow * 64 + b) * 4);
    }

    for (int ko = ko0; ko < ko0 + 8; ++ko) {
        U16B afr;                              // A-frag: m=cj, kdim=i (pad>=16)
        U16B bfr[4];
        if (lane < 32) {
            const int cj = cj0 + (lane & 15);
            const int c = cj >> 3, j = cj & 7;
            const int ib = (lane >> 4) * 8;
            // h[t] = bf16 W[ko,c,ib+t,j] (identical bits to the old cvtpk path)
            const unsigned short* wp = wb + (((size_t)ko * Cn + c) * 16 + ib) * 8 + j;
            #pragma unroll
            for (int t = 0; t < 8; ++t) afr.h[t] = wp[t * 8];
            #pragma unroll
            for (int nt = 0; nt < 4; ++nt)
                bfr[nt].u = *(const uint4*)(v1f + ((size_t)(ko * 4 + nt) * 32 + lane) * 8);
        } else {
            afr.u = make_uint4(0, 0, 0, 0);
            #pragma unroll
            for (int nt = 0; nt < 4; ++nt) bfr[nt].u = make_uint4(0, 0, 0, 0);
        }

        #pragma unroll
        for (int nt = 0; nt < 4; ++nt) {
            f4v acc = {0.f, 0.f, 0.f, 0.f};
            acc = __builtin_amdgcn_mfma_f32_16x16x32_bf16(afr.v, bfr[nt].v, acc, 0, 0, 0);
            float p = acc[0] * bflo(xq[nt].x) + acc[1] * bfhi(xq[nt].x)
                    + acc[2] * bflo(xq[nt].y) + acc[3] * bfhi(xq[nt].y);
            p += __shfl_xor(p, 16);            // j 0-3 + 4-7 within each c
            if (!(lane & 16)) {                // g=0 -> c0, g=2 -> c1
                const int cl = lane >> 5;
                const int b  = nt * 16 + (lane & 15);
                lds_p[cl][b][ko] = p;
            }
        }
    }
    __syncthreads();

    // softmax over k per (c,b): 128 items, 1 per thread (tid<128); cc -> bf16.
    if (tid < 128) {
        const int cl = tid >> 6, b = tid & 63;
        float a[32];
        float mx = -1e30f;
        #pragma unroll
        for (int k = 0; k < 32; ++k) { a[k] = lds_p[cl][b][k]; mx = fmaxf(mx, a[k]); }
        float sum = 0.f;
        #pragma unroll
        for (int k = 0; k < 32; ++k) { a[k] = __expf(a[k] - mx); sum += a[k]; }
        const float r = 1.0f / sum;
        const int c = cgi * 2 + cl;
        #pragma unroll
        for (int k = 0; k < 32; ++k)
            ccb[((size_t)k * Cn + c) * 64 + b] = f2bf(a[k] * r);
    }
}

// ---- K4: gemm2 — s[b,k,i] = sum_cj (cc*x)[b,cj] * W[k,cj,i] partials.
// Grid 512 = 32 k x 16 ksplits (32 ksteps each).  W from wb (plain uint4
// load, no cvtpk), cc from bf16.
__global__ __launch_bounds__(256) void kGemm2(const unsigned short* __restrict__ xb,
                                              const unsigned short* __restrict__ wb,
                                              const unsigned short* __restrict__ ccb,
                                              float* __restrict__ part2)
{
    const int ko    = blockIdx.x & 31;
    const int split = blockIdx.x >> 5;        // 0..15
    const int ks0   = split * 32;
    const int lane  = threadIdx.x & 63;
    const int m0    = (threadIdx.x >> 6) * 16;
    const int i     = lane & 15;
    const int cq    = lane >> 4;
    const int bg    = m0 + i;

    f4v acc = {0.f, 0.f, 0.f, 0.f};
    const unsigned short* arow = xb + (size_t)bg * KJ + cq * 8;
    const unsigned short* ccp = ccb + ((size_t)ko * Cn + ks0 * 4 + cq) * 64 + bg;

    for (int s = 0; s < 32; ++s) {
        const int ks = ks0 + s;
        const int c  = ks * 4 + cq;
        const uint4 au = *(const uint4*)(arow + (size_t)ks * 32);
        const float cv = bf1(ccp[s * 256]);
        U16B af;
        af.u.x = cvtpk(bflo(au.x) * cv, bfhi(au.x) * cv);
        af.u.y = cvtpk(bflo(au.y) * cv, bfhi(au.y) * cv);
        af.u.z = cvtpk(bflo(au.z) * cv, bfhi(au.z) * cv);
        af.u.w = cvtpk(bflo(au.w) * cv, bfhi(au.w) * cv);
        U16B bf;
        bf.u = *(const uint4*)(wb + (((size_t)ko * Cn + c) * 16 + i) * 8);
        acc = __builtin_amdgcn_mfma_f32_16x16x32_bf16(af.v, bf.v, acc, 0, 0, 0);
    }

    float* pb = part2 + (size_t)split * NOUT;
    const int col = lane & 15, rbase = (lane >> 4) * 4;
    #pragma unroll
    for (int r = 0; r < 4; ++r)
        pb[(size_t)(m0 + rbase + r) * 512 + ko * 16 + col] = acc[r];
}

// ---- K5: sq2 — out = squash(sum_splits part2).  Grid 512; block owns 16
// items (4 consecutive i); 16 subs = the 16 splits, LDS tree, 16 lanes finish.
__global__ __launch_bounds__(256) void kSq2(const float* __restrict__ part2,
                                            float* __restrict__ out)
{
    const int bid = blockIdx.x, tid = threadIdx.x;
    __shared__ float4 shB[256];
    const int itemL = tid & 15, sub = tid >> 4;   // sub 0..15
    const int item  = bid * 16 + itemL;           // 0..8191
    shB[tid] = *(const float4*)(part2 + (size_t)sub * NOUT + (size_t)item * 4);
    __syncthreads();
    if (tid < 16) {
        float4 s = make_float4(0.f, 0.f, 0.f, 0.f);
        #pragma unroll
        for (int sb = 0; sb < 16; ++sb) {
            const float4 q = shB[sb * 16 + tid];
            s.x += q.x; s.y += q.y; s.z += q.z; s.w += q.w;
        }
        float sq = (s.x * s.x + s.y * s.y) + (s.z * s.z + s.w * s.w);
        sq += __shfl_xor(sq, 1);
        sq += __shfl_xor(sq, 2);
        const float f = (sq / (1.0f + sq)) * rsqrtf(sq + EPSf);
        *(float4*)(out + (size_t)(bid * 16 + tid) * 4) =
            make_float4(s.x * f, s.y * f, s.z * f, s.w * f);
    }
}

extern "C" void kernel_launch(void* const* d_in, const int* in_sizes, int n_in,
                              void* d_out, int out_size, void* d_ws, size_t ws_size,
                              hipStream_t stream)
{
    const float* x = (const float*)d_in[0];   // [64,2048,8]
    const float* W = (const float*)d_in[1];   // [32,2048,16,8]
    float* out = (float*)d_out;               // [64,32,16]
    float* wsf = (float*)d_ws;

    unsigned short* wb    = (unsigned short*)(wsf);                  // 16 MiB
    float*          part1 = wsf + 4194304;                           // 8 MiB
    unsigned short* ccb   = (unsigned short*)(wsf + 4194304);        // alias
    unsigned short* xb    = (unsigned short*)(wsf + 6291456);        // 2 MiB
    unsigned short* xT2   = (unsigned short*)(wsf + 6815744);        // 2 MiB
    float*          part2 = wsf + 6815744;                           // alias
    unsigned short* v1f   = (unsigned short*)(wsf + 7340032);        // 64 KiB

    kGemm1  <<<512,  256, 0, stream>>>(x, W, part1, wb, xb, xT2);
    kSq1    <<<512,  256, 0, stream>>>(part1, v1f);
    kAgrSmax<<<1024, 256, 0, stream>>>(wb, v1f, xT2, ccb);
    kGemm2  <<<512,  256, 0, stream>>>(xb, wb, ccb, part2);
    kSq2    <<<512,  256, 0, stream>>>(part2, out);
}